// Round 7
// baseline (23.611 us; speedup 1.0000x reference)
//
#include <hip/hip_runtime.h>

// Polyrigid: per-voxel weighted log-euclidean blend of K=8 affine transforms,
// expm applied directly to the grid point (Taylor-on-vector), then view xform.
// D,H,W = 64,128,128 ; N = 1048576 ; K = 8.
//
// Round 7: consecutive-voxel layout. Each thread owns 4 CONSECUTIVE voxels:
//  - weight loads: thread reads exactly one 128-B line (8x nt dwordx4)
//  - output: 48 contiguous bytes -> 3x nt float4 stores (16B-aligned)
//  - nt hints keep the zero-reuse streams out of L2's way
// logT/view stay uniform scalars (SGPRs). Taylor through L^4/4!
// (remainder ~7e-5 << 2.28e-2 threshold).

#define DDIM 64
#define HDIM 128
#define WDIM 128
#define KCOMP 8
#define NVOX (DDIM * HDIM * WDIM)
#define VPT 4                      // consecutive voxels per thread
#define BLK 256

typedef float f32x4 __attribute__((ext_vector_type(4)));

__global__ __launch_bounds__(BLK) void polyrigid_kernel(
    const float* __restrict__ weights,    // (N,8)
    const float* __restrict__ log_rots,   // (8,9)
    const float* __restrict__ log_trans,  // (8,3)
    const float* __restrict__ view,       // (4,4)
    float* __restrict__ out)              // (N,3)
{
    const int t = threadIdx.x;
    const int base = blockIdx.x * (BLK * VPT);   // 1024 consecutive voxels per block
    const int i0 = base + t * VPT;               // this thread's 4 consecutive voxels

    // ---- weights: this thread's 128 B = exactly one cacheline (8x nt dwordx4) ----
    f32x4 w4[VPT][2];
    {
        const f32x4* wp = (const f32x4*)(weights + (size_t)i0 * KCOMP);
        #pragma unroll
        for (int j = 0; j < VPT; ++j) {
            w4[j][0] = __builtin_nontemporal_load(wp + 2 * j);
            w4[j][1] = __builtin_nontemporal_load(wp + 2 * j + 1);
        }
    }

    // ---- uniform loads: compile-time offsets off uniform pointers -> s_load/SGPR ----
    float lt[KCOMP * 12];                 // logT row k: [rot0..rot8, tr0..tr2]
    #pragma unroll
    for (int k = 0; k < KCOMP; ++k) {
        #pragma unroll
        for (int j = 0; j < 9; ++j) lt[k * 12 + j] = log_rots[k * 9 + j];
        #pragma unroll
        for (int j = 0; j < 3; ++j) lt[k * 12 + 9 + j] = log_trans[k * 3 + j];
    }
    float vV[12];                         // view rows 0..2 (row 3 = [0,0,0,1])
    #pragma unroll
    for (int j = 0; j < 12; ++j) vV[j] = view[j];

    // grid coords: i0..i0+3 lie in one w-row (VPT | WDIM). x uniform per block.
    const float x = fmaf((float)(base >> 14), 2.0f / 63.0f, -1.0f);
    const float y = fmaf((float)((i0 >> 7) & (HDIM - 1)), 2.0f / 127.0f, -1.0f);
    const int wi0 = i0 & (WDIM - 1);

    const float rk[3] = {0.5f, 1.0f / 3.0f, 0.25f};
    float o[VPT * 3];                     // 4 voxels x 3 coords = 48 B contiguous

    #pragma unroll
    for (int j = 0; j < VPT; ++j) {
        const float wk[8] = {w4[j][0].x, w4[j][0].y, w4[j][0].z, w4[j][0].w,
                             w4[j][1].x, w4[j][1].y, w4[j][1].z, w4[j][1].w};

        // L = sum_k wk * logT[k]   (3x4; bottom row of the 4x4 is zero)
        float L[12];
        #pragma unroll
        for (int jj = 0; jj < 12; ++jj) {
            float acc = wk[0] * lt[jj];
            #pragma unroll
            for (int k = 1; k < KCOMP; ++k) acc = fmaf(wk[k], lt[k * 12 + jj], acc);
            L[jj] = acc;
        }

        const float z = fmaf((float)(wi0 + j), 2.0f / 127.0f, -1.0f);

        // q = exp(L) @ [x,y,z,1] (xyz part), Taylor-on-vector through L^4/4!
        float a0 = fmaf(L[0], x, fmaf(L[1], y, fmaf(L[2],  z, L[3])));
        float a1 = fmaf(L[4], x, fmaf(L[5], y, fmaf(L[6],  z, L[7])));
        float a2 = fmaf(L[8], x, fmaf(L[9], y, fmaf(L[10], z, L[11])));
        float q0 = x + a0, q1 = y + a1, q2 = z + a2;
        #pragma unroll
        for (int s = 0; s < 3; ++s) {
            const float b0 = fmaf(L[0], a0, fmaf(L[1], a1, L[2]  * a2)) * rk[s];
            const float b1 = fmaf(L[4], a0, fmaf(L[5], a1, L[6]  * a2)) * rk[s];
            const float b2 = fmaf(L[8], a0, fmaf(L[9], a1, L[10] * a2)) * rk[s];
            q0 += b0; q1 += b1; q2 += b2;
            a0 = b0; a1 = b1; a2 = b2;
        }

        // p = V @ [q,1]  (rows 0..2; p[3] == 1 exactly, no divide)
        o[j * 3 + 0] = fmaf(vV[0], q0, fmaf(vV[1], q1, fmaf(vV[2],  q2, vV[3])));
        o[j * 3 + 1] = fmaf(vV[4], q0, fmaf(vV[5], q1, fmaf(vV[6],  q2, vV[7])));
        o[j * 3 + 2] = fmaf(vV[8], q0, fmaf(vV[9], q1, fmaf(vV[10], q2, vV[11])));
    }

    // ---- 48 contiguous bytes -> 3x nt float4 stores (i0*12 B is 16B-aligned) ----
    f32x4* op = (f32x4*)(out + (size_t)i0 * 3);
    #pragma unroll
    for (int c = 0; c < 3; ++c) {
        f32x4 v = {o[4 * c + 0], o[4 * c + 1], o[4 * c + 2], o[4 * c + 3]};
        __builtin_nontemporal_store(v, op + c);
    }
}

extern "C" void kernel_launch(void* const* d_in, const int* in_sizes, int n_in,
                              void* d_out, int out_size, void* d_ws, size_t ws_size,
                              hipStream_t stream) {
    const float* weights    = (const float*)d_in[0];  // (N,8)
    const float* log_rots   = (const float*)d_in[1];  // (8,9)
    const float* log_trans  = (const float*)d_in[2];  // (8,3)
    // d_in[3] = sample_points (N,4) — recomputed on-device from voxel index
    const float* view       = (const float*)d_in[4];  // (4,4)
    float* out = (float*)d_out;                        // (N,3)

    const int grid = NVOX / (BLK * VPT);               // 1024
    polyrigid_kernel<<<grid, BLK, 0, stream>>>(weights, log_rots, log_trans, view, out);
}

// Round 8
// 13.526 us; speedup vs baseline: 1.7456x; 1.7456x over previous
//
#include <hip/hip_runtime.h>

// Polyrigid: per-voxel weighted log-euclidean blend of K=8 affine transforms,
// expm applied directly to the grid point (Taylor-on-vector), then view xform.
// D,H,W = 64,128,128 ; N = 1048576 ; K = 8.
//
// Round 8: exact revert to Round 6 (best: 13.69 us). R7's consecutive-voxel
// layout was wave-strided (lane i at byte i*128 -> 64 lines per instruction)
// and regressed to 23.6 us. Interleaved layout = coalesced: lane i at
// base + i*16 B per dwordx4. nt hints on the zero-reuse weight stream,
// logT/view uniform scalars (SGPRs), Taylor through L^4/4! (rem ~7e-5).

#define DDIM 64
#define HDIM 128
#define WDIM 128
#define KCOMP 8
#define NVOX (DDIM * HDIM * WDIM)
#define VPT 4                      // voxels per thread (interleaved by BLK)
#define BLK 256

struct f3 { float x, y, z; };
typedef float f32x4 __attribute__((ext_vector_type(4)));

__global__ __launch_bounds__(BLK) void polyrigid_kernel(
    const float* __restrict__ weights,    // (N,8)
    const float* __restrict__ log_rots,   // (8,9)
    const float* __restrict__ log_trans,  // (8,3)
    const float* __restrict__ view,       // (4,4)
    float* __restrict__ out)              // (N,3)
{
    const int t = threadIdx.x;
    const int base = blockIdx.x * (BLK * VPT);   // 1024 consecutive voxels per block

    // ---- issue all 8 weight loads first (coalesced dwordx4, nontemporal) ----
    f32x4 w4[VPT][2];
    #pragma unroll
    for (int j = 0; j < VPT; ++j) {
        const int i = base + j * BLK + t;
        const f32x4* wp = (const f32x4*)(weights + (size_t)i * KCOMP);
        w4[j][0] = __builtin_nontemporal_load(wp);
        w4[j][1] = __builtin_nontemporal_load(wp + 1);
    }

    // ---- uniform loads: compile-time offsets off uniform pointers -> s_load,
    //      scalar floats stay in SGPRs (no vector types here!) ----
    float lt[KCOMP * 12];                 // logT row k: [rot0..rot8, tr0..tr2]
    #pragma unroll
    for (int k = 0; k < KCOMP; ++k) {
        #pragma unroll
        for (int j = 0; j < 9; ++j) lt[k * 12 + j] = log_rots[k * 9 + j];
        #pragma unroll
        for (int j = 0; j < 3; ++j) lt[k * 12 + 9 + j] = log_trans[k * 3 + j];
    }
    float vV[12];                         // view rows 0..2 (row 3 = [0,0,0,1])
    #pragma unroll
    for (int j = 0; j < 12; ++j) vV[j] = view[j];

    // grid coords derivable from index; di is uniform per block (1024-aligned span)
    const int   di = base >> 14;
    const float x  = fmaf((float)di, 2.0f / 63.0f, -1.0f);
    const float z  = fmaf((float)(t & (WDIM - 1)), 2.0f / 127.0f, -1.0f);
    const int   hb = (base >> 7) + (t >> 7);     // hi = (hb + 2j) & 127

    const float rk[3] = {0.5f, 1.0f / 3.0f, 0.25f};

    #pragma unroll
    for (int j = 0; j < VPT; ++j) {
        const int i = base + j * BLK + t;
        const float wk[8] = {w4[j][0].x, w4[j][0].y, w4[j][0].z, w4[j][0].w,
                             w4[j][1].x, w4[j][1].y, w4[j][1].z, w4[j][1].w};

        // L = sum_k wk * logT[k]   (3x4; bottom row of the 4x4 is zero)
        float L[12];
        #pragma unroll
        for (int jj = 0; jj < 12; ++jj) {
            float acc = wk[0] * lt[jj];
            #pragma unroll
            for (int k = 1; k < KCOMP; ++k) acc = fmaf(wk[k], lt[k * 12 + jj], acc);
            L[jj] = acc;
        }

        const float y = fmaf((float)((hb + 2 * j) & (HDIM - 1)), 2.0f / 127.0f, -1.0f);

        // q = exp(L) @ [x,y,z,1] (xyz part), Taylor-on-vector through L^4/4!
        float a0 = fmaf(L[0], x, fmaf(L[1], y, fmaf(L[2],  z, L[3])));
        float a1 = fmaf(L[4], x, fmaf(L[5], y, fmaf(L[6],  z, L[7])));
        float a2 = fmaf(L[8], x, fmaf(L[9], y, fmaf(L[10], z, L[11])));
        float q0 = x + a0, q1 = y + a1, q2 = z + a2;
        #pragma unroll
        for (int s = 0; s < 3; ++s) {
            const float b0 = fmaf(L[0], a0, fmaf(L[1], a1, L[2]  * a2)) * rk[s];
            const float b1 = fmaf(L[4], a0, fmaf(L[5], a1, L[6]  * a2)) * rk[s];
            const float b2 = fmaf(L[8], a0, fmaf(L[9], a1, L[10] * a2)) * rk[s];
            q0 += b0; q1 += b1; q2 += b2;
            a0 = b0; a1 = b1; a2 = b2;
        }

        // p = V @ [q,1]  (rows 0..2; p[3] == 1 exactly, no divide)
        f3 o;
        o.x = fmaf(vV[0], q0, fmaf(vV[1], q1, fmaf(vV[2],  q2, vV[3])));
        o.y = fmaf(vV[4], q0, fmaf(vV[5], q1, fmaf(vV[6],  q2, vV[7])));
        o.z = fmaf(vV[8], q0, fmaf(vV[9], q1, fmaf(vV[10], q2, vV[11])));
        ((f3*)out)[i] = o;
    }
}

extern "C" void kernel_launch(void* const* d_in, const int* in_sizes, int n_in,
                              void* d_out, int out_size, void* d_ws, size_t ws_size,
                              hipStream_t stream) {
    const float* weights    = (const float*)d_in[0];  // (N,8)
    const float* log_rots   = (const float*)d_in[1];  // (8,9)
    const float* log_trans  = (const float*)d_in[2];  // (8,3)
    // d_in[3] = sample_points (N,4) — recomputed on-device from voxel index
    const float* view       = (const float*)d_in[4];  // (4,4)
    float* out = (float*)d_out;                        // (N,3)

    const int grid = NVOX / (BLK * VPT);               // 1024
    polyrigid_kernel<<<grid, BLK, 0, stream>>>(weights, log_rots, log_trans, view, out);
}